// Round 5
// baseline (635.082 us; speedup 1.0000x reference)
//
#include <hip/hip_runtime.h>

typedef __attribute__((ext_vector_type(8))) short short8;
typedef __attribute__((ext_vector_type(4))) float floatx4;
typedef __attribute__((ext_vector_type(4))) unsigned int uintx4;

__device__ __forceinline__ short f2bf(float f) {
    unsigned u = __builtin_bit_cast(unsigned, f);
    u = (u + 0x7FFFu + ((u >> 16) & 1u)) >> 16;
    return (short)u;
}

// ---------------------------------------------------------------------------
// Workspace layout (bf16 element offsets):
//   w1T0=0, w1T1=65536, w1T2=196608, w2T0=458752, w2T1=524288, w2T2=589824
//   xg0 = 655360  (4096*256)
//   xg1 = 1703936 (4096*512)
//   xg2 = 3801088 (4096*1024)
//   sorted pid sp (int2, 3 scales x 256) @ bf16 7995392  (6144 B)
//   window maps  (int) @ bf16 7998464: jst1[1025] @ +0, jst2[257] @ +1040
// ---------------------------------------------------------------------------

// Bitonic sort of 256 (s, p) pairs per scale, ascending by s; then build
// window->sorted-range maps for the streaming scales (1 and 2).
__global__ __launch_bounds__(256) void sort_pid(
    const int* __restrict__ pid0, const int* __restrict__ pid1, const int* __restrict__ pid2,
    unsigned short* __restrict__ wsb)
{
    __shared__ int ks[256];
    __shared__ int vs[256];
    const int* pid = (blockIdx.x == 0) ? pid0 : (blockIdx.x == 1) ? pid1 : pid2;
    int t = threadIdx.x;
    ks[t] = pid[t];
    vs[t] = t;
    __syncthreads();
    for (int k = 2; k <= 256; k <<= 1) {
        for (int j = k >> 1; j > 0; j >>= 1) {
            int ixj = t ^ j;
            if (ixj > t) {
                int a = ks[t], b = ks[ixj];
                bool asc = ((t & k) == 0);
                if (asc ? (a > b) : (a < b)) {
                    ks[t] = b; ks[ixj] = a;
                    int va = vs[t]; vs[t] = vs[ixj]; vs[ixj] = va;
                }
            }
            __syncthreads();
        }
    }
    int2* sp = (int2*)(wsb + 7995392) + blockIdx.x * 256;
    sp[t] = make_int2(ks[t], vs[t]);

    // window maps: jst[w] = lower_bound(ks, w*4)  (float4 windows)
    if (blockIdx.x >= 1) {
        int W = (blockIdx.x == 1) ? 1024 : 256;     // HW/4
        int* jst = (int*)(wsb + 7998464) + ((blockIdx.x == 2) ? 1040 : 0);
        for (int w = t; w <= W; w += 256) {
            int target = w * 4;
            int lo = 0, hi = 256;
            while (lo < hi) { int mid = (lo + hi) >> 1; if (ks[mid] < target) lo = mid + 1; else hi = mid; }
            jst[w] = lo;
        }
    }
}

// ---------------------------------------------------------------------------
// Streaming extract for dense scales: read the (b, CH-channel) planes with
// fully-coalesced float4 loads (wave = 1KB ascending), pick out sampled
// positions via the window map into LDS tile[CH][256], then transpose-write
// each sorted sample's CH-chunk as contiguous 16B stores to x[row][C].
// ---------------------------------------------------------------------------
template<int CH, int IT, int HW>
__device__ __forceinline__ void stream_gather(
    const float* __restrict__ featb, const int2* __restrict__ sp, const int* __restrict__ jst,
    unsigned short* __restrict__ xg, int C, int b, int cg,
    unsigned short* tileRaw, int t)
{
    unsigned short (*tile)[256] = (unsigned short (*)[256])tileRaw;
    int cbase = cg * CH;
    #pragma unroll
    for (int it = 0; it < IT; ++it) {
        int w = it * 256 + t;              // float4 window index in the plane
        int js = jst[w], je = jst[w + 1];
        int pos = w * 4;
        #pragma unroll 8
        for (int c = 0; c < CH; ++c) {
            const float* plane = featb + (size_t)(cbase + c) * HW;
            float4 v = ((const float4*)plane)[w];
            for (int j = js; j < je; ++j) {
                int s = sp[j].x - pos;     // 0..3
                float val = (s & 2) ? ((s & 1) ? v.w : v.z) : ((s & 1) ? v.y : v.x);
                tile[c][j] = (unsigned short)f2bf(val);
            }
        }
    }
    __syncthreads();
    // thread t owns sorted sample t
    int2 e = sp[t];
    int row = b * 256 + e.y;
    unsigned short* dst = xg + (size_t)row * C + cbase;
    #pragma unroll
    for (int c8 = 0; c8 < CH / 8; ++c8) {
        short8 rv;
        #pragma unroll
        for (int k = 0; k < 8; ++k) rv[k] = (short)tile[c8 * 8 + k][t];
        *(short8*)(dst + c8 * 8) = rv;
    }
}

// ---------------------------------------------------------------------------
// Blocks [0,256):    scale1 streaming extract (16 b x 16 cg, CH=32)
// Blocks [256,512):  scale0 sorted direct gather (no LDS, 16 loads/thread)
// Blocks [512,768):  scale2 streaming extract (16 b x 16 cg, CH=64)
// Blocks [768,1408): weight transpose+cast (overlaps)
// ---------------------------------------------------------------------------
__global__ __launch_bounds__(256) void gather_prep(
    const float* __restrict__ feat0, const float* __restrict__ feat1, const float* __restrict__ feat2,
    const float* __restrict__ w10, const float* __restrict__ w11, const float* __restrict__ w12,
    const float* __restrict__ w20, const float* __restrict__ w21, const float* __restrict__ w22,
    unsigned short* __restrict__ wsb)
{
    __shared__ __align__(16) unsigned char smemRaw[32768];
    int blk = blockIdx.x;
    int t = threadIdx.x;
    const int2* spb = (const int2*)(wsb + 7995392);
    const int* jstb = (const int*)(wsb + 7998464);

    if (blk < 256) {            // ---- scale1 streaming: HW=4096, C=512 ----
        int b = blk >> 4, cg = blk & 15;
        const float* featb = feat1 + (size_t)b * 512 * 4096;
        stream_gather<32, 4, 4096>(featb, spb + 256, jstb, wsb + 1703936, 512, b, cg,
                                   (unsigned short*)smemRaw, t);
        return;
    }
    if (blk < 512) {            // ---- scale0 direct: HW=16384, C=256 ----
        int l = blk - 256;
        int j = l * 16 + (t >> 4);         // sorted row index 0..4095
        int chunk16 = t & 15;              // 16-channel chunk
        int b = j >> 8;
        int2 e = spb[j & 255];
        const float* gp = feat0 + (size_t)b * 256 * 16384 + (size_t)(chunk16 * 16) * 16384 + e.x;
        float v[16];
        #pragma unroll
        for (int k = 0; k < 16; ++k) v[k] = gp[(size_t)k * 16384];   // 16 independent loads
        int orow = b * 256 + e.y;
        unsigned short* dst = wsb + 655360 + (size_t)orow * 256 + chunk16 * 16;
        short8 s0, s1;
        #pragma unroll
        for (int k = 0; k < 8; ++k) { s0[k] = f2bf(v[k]); s1[k] = f2bf(v[8 + k]); }
        *(short8*)dst = s0;
        *(short8*)(dst + 8) = s1;
        return;
    }
    if (blk < 768) {            // ---- scale2 streaming: HW=1024, C=1024 ----
        int l = blk - 512, b = l >> 4, cg = l & 15;
        const float* featb = feat2 + (size_t)b * 1024 * 1024;
        stream_gather<64, 1, 1024>(featb, spb + 512, jstb + 1040, wsb + 3801088, 1024, b, cg,
                                   (unsigned short*)smemRaw, t);
        return;
    }

    // ---- weight transpose+cast fp32 w[K][256] -> bf16 wT[256][K] ----
    blk -= 768;
    float (*wt)[33] = (float (*)[33])smemRaw;
    const float* in; unsigned short* out; int K, t0;
    if (blk < 64)       { in = w10; out = wsb;          K = 256;  t0 = 0; }
    else if (blk < 192) { in = w11; out = wsb + 65536;  K = 512;  t0 = 64; }
    else if (blk < 448) { in = w12; out = wsb + 196608; K = 1024; t0 = 192; }
    else if (blk < 512) { in = w20; out = wsb + 458752; K = 256;  t0 = 448; }
    else if (blk < 576) { in = w21; out = wsb + 524288; K = 256;  t0 = 512; }
    else                { in = w22; out = wsb + 589824; K = 256;  t0 = 576; }
    int tile_id = blk - t0;
    int tk = K >> 5;
    int k0 = (tile_id % tk) << 5;
    int n0 = (tile_id / tk) << 5;
    int j = t & 31, i0 = (t >> 5) << 2;
    #pragma unroll
    for (int u = 0; u < 4; u++)
        wt[i0 + u][j] = in[(size_t)(k0 + i0 + u) * 256 + (n0 + j)];
    __syncthreads();
    int kf = t & 31, nf0 = (t >> 5) << 2;
    #pragma unroll
    for (int u = 0; u < 4; u++)
        out[(size_t)(n0 + nf0 + u) * K + (k0 + kf)] = (unsigned short)f2bf(wt[kf][nf0 + u]);
}

// ---------------------------------------------------------------------------
// MLP(2-layer, relu) + L2-normalize, reading compact bf16 x from workspace.
// Block: 32 rows x 256 cols. 4 waves: wave w -> rows (w&1)*16, cols (w>>1)*128.
// ---------------------------------------------------------------------------
__global__ __launch_bounds__(256, 2) void fused_mlp(
    const float* __restrict__ b1_0, const float* __restrict__ b1_1, const float* __restrict__ b1_2,
    const float* __restrict__ b2_0, const float* __restrict__ b2_1, const float* __restrict__ b2_2,
    const unsigned short* __restrict__ wsb,
    float* __restrict__ out)
{
    __shared__ __align__(16) unsigned short smem[26944];
    unsigned short* wsS = smem;            // 256*72
    unsigned short* xs  = smem + 18432;    // 32*72
    unsigned short* hs  = smem + 18432;    // 32*264
    float* rs = (float*)(smem + 26880);    // 32 floats

    int blk = blockIdx.x;
    int scale = 2 - (blk >> 7);            // big-K blocks dispatched first
    int mblk = blk & 127;

    const float* b1; const float* b2;
    const unsigned short* w1T; const unsigned short* w2T; const unsigned short* xg;
    int C; size_t outBase;
    if (scale == 0) { b1 = b1_0; b2 = b2_0; w1T = wsb;          w2T = wsb + 458752;
                      xg = wsb + 655360;  C = 256;  outBase = 0; }
    else if (scale == 1) { b1 = b1_1; b2 = b2_1; w1T = wsb + 65536;  w2T = wsb + 524288;
                      xg = wsb + 1703936; C = 512;  outBase = 1048576; }
    else            { b1 = b1_2; b2 = b2_2; w1T = wsb + 196608; w2T = wsb + 589824;
                      xg = wsb + 3801088; C = 1024; outBase = 2097152; }

    int t = threadIdx.x;
    int wid = t >> 6, lane = t & 63, quad = lane >> 4, l15 = lane & 15;
    int r0 = (wid & 1) << 4;          // row offset of this wave
    int c0 = (wid >> 1) << 7;         // col offset of this wave

    int gr = t >> 3;                  // 0..31
    int gk = (t & 7) << 3;            // 0,8,...,56
    int row_g = (mblk << 5) + gr;
    const unsigned short* xrow = xg + (size_t)row_g * C;

    floatx4 acc[8];
    #pragma unroll
    for (int f = 0; f < 8; f++) acc[f] = (floatx4){0.f, 0.f, 0.f, 0.f};

    // ---------------- GEMM1: x[32,C] @ w1[C,256] ----------------
    for (int kc = 0; kc < C; kc += 64) {
        *(short8*)(xs + gr * 72 + gk) = *(const short8*)(xrow + kc + gk);
        {
            const uintx4* src = (const uintx4*)(w1T + (size_t)t * C + kc);
            uintx4* dst = (uintx4*)(wsS + t * 72);
            #pragma unroll
            for (int j2 = 0; j2 < 8; j2++) dst[j2] = src[j2];
        }
        __syncthreads();
        const unsigned short* aRow = xs + (r0 + l15) * 72;
        const unsigned short* bRow = wsS + (c0 + l15) * 72;
        #pragma unroll
        for (int ks = 0; ks < 2; ks++) {
            short8 af = *(const short8*)(aRow + ks * 32 + quad * 8);
            #pragma unroll
            for (int f = 0; f < 8; f++) {
                short8 bf = *(const short8*)(bRow + f * (16 * 72) + ks * 32 + quad * 8);
                acc[f] = __builtin_amdgcn_mfma_f32_16x16x32_bf16(af, bf, acc[f], 0, 0, 0);
            }
        }
        __syncthreads();
    }

    // ---------------- h = relu(acc + b1) -> LDS (bf16) ----------------
    {
        float bias1[8];
        #pragma unroll
        for (int f = 0; f < 8; f++) bias1[f] = b1[c0 + f * 16 + l15];
        #pragma unroll
        for (int f = 0; f < 8; f++)
            #pragma unroll
            for (int reg = 0; reg < 4; reg++) {
                float h = fmaxf(acc[f][reg] + bias1[f], 0.f);
                hs[(r0 + quad * 4 + reg) * 264 + (c0 + f * 16 + l15)] = (unsigned short)f2bf(h);
            }
    }

    // ---------------- GEMM2: h[32,256] @ w2[256,256] ----------------
    #pragma unroll
    for (int f = 0; f < 8; f++) acc[f] = (floatx4){0.f, 0.f, 0.f, 0.f};
    const unsigned short* hA = hs + (r0 + l15) * 264;
    for (int kc = 0; kc < 256; kc += 64) {
        {
            const uintx4* src = (const uintx4*)(w2T + (size_t)t * 256 + kc);
            uintx4* dst = (uintx4*)(wsS + t * 72);
            #pragma unroll
            for (int j2 = 0; j2 < 8; j2++) dst[j2] = src[j2];
        }
        __syncthreads();
        const unsigned short* bRow = wsS + (c0 + l15) * 72;
        #pragma unroll
        for (int ks = 0; ks < 2; ks++) {
            short8 af = *(const short8*)(hA + kc + ks * 32 + quad * 8);
            #pragma unroll
            for (int f = 0; f < 8; f++) {
                short8 bf = *(const short8*)(bRow + f * (16 * 72) + ks * 32 + quad * 8);
                acc[f] = __builtin_amdgcn_mfma_f32_16x16x32_bf16(af, bf, acc[f], 0, 0, 0);
            }
        }
        __syncthreads();
    }

    // ---------------- epilogue: y = acc + b2; y / (||y|| + 1e-7) ----------------
    {
        float bias2[8];
        #pragma unroll
        for (int f = 0; f < 8; f++) bias2[f] = b2[c0 + f * 16 + l15];
        float psq[4] = {0.f, 0.f, 0.f, 0.f};
        #pragma unroll
        for (int f = 0; f < 8; f++)
            #pragma unroll
            for (int reg = 0; reg < 4; reg++) {
                float yv = acc[f][reg] + bias2[f];
                acc[f][reg] = yv;
                psq[reg] += yv * yv;
            }
        #pragma unroll
        for (int m = 1; m < 16; m <<= 1)
            #pragma unroll
            for (int reg = 0; reg < 4; reg++)
                psq[reg] += __shfl_xor(psq[reg], m, 16);

        if (t < 32) rs[t] = 0.f;
        __syncthreads();
        if (l15 == 0) {
            #pragma unroll
            for (int reg = 0; reg < 4; reg++)
                atomicAdd(&rs[r0 + quad * 4 + reg], psq[reg]);
        }
        __syncthreads();

        #pragma unroll
        for (int f = 0; f < 8; f++)
            #pragma unroll
            for (int reg = 0; reg < 4; reg++) {
                int row = r0 + quad * 4 + reg;
                float inv = 1.f / (sqrtf(rs[row]) + 1e-7f);
                out[outBase + (size_t)((mblk << 5) + row) * 256 + (c0 + f * 16 + l15)] =
                    acc[f][reg] * inv;
            }
    }
}

extern "C" void kernel_launch(void* const* d_in, const int* in_sizes, int n_in,
                              void* d_out, int out_size, void* d_ws, size_t ws_size,
                              hipStream_t stream)
{
    (void)n_in; (void)out_size; (void)ws_size;
    bool dict = (in_sizes[1] == 256);
    const float *feat[3], *w1[3], *b1[3], *w2[3], *b2[3];
    const int* pid[3];
    for (int i = 0; i < 3; i++) {
        if (dict) {
            feat[i] = (const float*)d_in[i * 6 + 0];
            pid[i]  = (const int*)  d_in[i * 6 + 1];
            w1[i]   = (const float*)d_in[i * 6 + 2];
            b1[i]   = (const float*)d_in[i * 6 + 3];
            w2[i]   = (const float*)d_in[i * 6 + 4];
            b2[i]   = (const float*)d_in[i * 6 + 5];
        } else {
            feat[i] = (const float*)d_in[i];
            pid[i]  = (const int*)  d_in[3 + i];
            w1[i]   = (const float*)d_in[6 + 4 * i + 0];
            b1[i]   = (const float*)d_in[6 + 4 * i + 1];
            w2[i]   = (const float*)d_in[6 + 4 * i + 2];
            b2[i]   = (const float*)d_in[6 + 4 * i + 3];
        }
    }
    unsigned short* wsb = (unsigned short*)d_ws;   // needs ~16 MB of workspace
    sort_pid<<<3, 256, 0, stream>>>(pid[0], pid[1], pid[2], wsb);
    gather_prep<<<1408, 256, 0, stream>>>(feat[0], feat[1], feat[2],
                                          w1[0], w1[1], w1[2],
                                          w2[0], w2[1], w2[2], wsb);
    fused_mlp<<<384, 256, 0, stream>>>(b1[0], b1[1], b1[2],
                                       b2[0], b2[1], b2[2],
                                       wsb, (float*)d_out);
}